// Round 2
// baseline (253.231 us; speedup 1.0000x reference)
//
#include <hip/hip_runtime.h>
#include <hip/hip_bf16.h>

// DilatedMSA round 7: SINGLE fused kernel.
// Attention is block-local (softmax over g in [0,256) of one (b,l)), so one
// workgroup owns (bl, head, q-half): computes Q/K/V tiles straight from fp32
// x and W (in-lane cvt to bf16 fragments -- x rows ARE the fragment layout,
// no x staging), K/V^T in LDS, Q in regs, then the round-6 attention loop.
// Deletes the 100MB qkv HBM round-trip, 2 kernel launches, and the convw pass.
// LDS 79 KB -> 2 blocks/CU. XCD-chunked swizzle colocates same-bl blocks.

typedef __bf16 bf16x8 __attribute__((ext_vector_type(8)));
typedef float  f32x4  __attribute__((ext_vector_type(4)));

#define MFMA16(a, b, c) __builtin_amdgcn_mfma_f32_16x16x32_bf16((a), (b), (c), 0, 0, 0)

namespace dmsa {

constexpr int G  = 256;    // tokens per (b,l)
constexpr int C  = 128;    // channels
constexpr int HD = 64;     // head dim
// fold log2(e)/sqrt(128) into Q -> attn does exp2(s) directly
constexpr float QSCALE = 1.4426950408889634f * 0.08838834764831845f;

__device__ __forceinline__ unsigned pack2(float a, float b) {
    union { __hip_bfloat162 h; unsigned u; } c;
    c.h = __float22bfloat162_rn(make_float2(a, b));   // v_cvt_pk_bf16_f32
    return c.u;
}
__device__ __forceinline__ uint2 pack4(float a, float b, float c, float d) {
    uint2 r; r.x = pack2(a, b); r.y = pack2(c, d); return r;
}
__device__ __forceinline__ bf16x8 lds8(const ushort* p) { return *(const bf16x8*)p; }

// 8 consecutive fp32 -> bf16x8 fragment (2x float4 + packed cvt)
__device__ __forceinline__ bf16x8 ld8f(const float* __restrict__ p) {
    float t[8];
    *(float4*)t       = *(const float4*)p;
    *(float4*)(t + 4) = *(const float4*)(p + 4);
    union { uint4 u; bf16x8 v; } c;
    c.u.x = pack2(t[0], t[1]); c.u.y = pack2(t[2], t[3]);
    c.u.z = pack2(t[4], t[5]); c.u.w = pack2(t[6], t[7]);
    return c.v;
}

// ---------------------------------------------------------------------------
// grid 2048 = (bl 512) x (h 2) x (qh 2), block 256 (4 waves).
// Wave wv: queries q0 = qh*128 + wv*32 (Q in regs); K/V-GEMM rows wv*64..+64.
// ---------------------------------------------------------------------------
__global__ __launch_bounds__(256, 2)
void fused(const float* __restrict__ x, const float* __restrict__ W,
           const float* __restrict__ bias, float* __restrict__ out)
{
    __shared__ ushort kc[G * 72];        // K [256 g][64 c' +pad8]; head doubles as Q-stage
    __shared__ ushort vc[HD * 264];      // V^T [64 c'][256 g +pad8]
    __shared__ ushort pt[4 * 32 * 40];   // per-wave P [32 q][32 k +pad8]

    const int tid = threadIdx.x, wv = tid >> 6, lane = tid & 63;
    const int l16 = lane & 15, quad = lane >> 4;

    // XCD-chunked bijective swizzle (2048 % 8 == 0): physical b on XCD b%8
    // walks logical L consecutively -> the 4 blocks sharing one bl colocate.
    const int b  = blockIdx.x;
    const int L  = ((b & 7) << 8) | (b >> 3);
    const int bl = L >> 2, h = (L >> 1) & 1, qh = L & 1;

    const float* xb = x + (size_t)bl * G * C;
    const float* Wq = W + (size_t)(h * HD) * C;
    const float* Wk = W + (size_t)(C + h * HD) * C;
    const float* Wv = W + (size_t)(2 * C + h * HD) * C;

    const f32x4 z4 = {0.f, 0.f, 0.f, 0.f};

    // ---- phase Q: Q^T [c'=64][q=32/wave]. A=Wq(m=c'), B=x(n=q), K-dim=ch.
    const int q0 = qh * 128 + wv * 32;
    f32x4 qacc[4][2];
    #pragma unroll
    for (int mi = 0; mi < 4; ++mi)
        #pragma unroll
        for (int ni = 0; ni < 2; ++ni) qacc[mi][ni] = z4;

    #pragma unroll
    for (int kk = 0; kk < 4; ++kk) {
        bf16x8 bq[2];
        #pragma unroll
        for (int ni = 0; ni < 2; ++ni)
            bq[ni] = ld8f(xb + (size_t)(q0 + ni * 16 + l16) * C + kk * 32 + quad * 8);
        #pragma unroll
        for (int mi = 0; mi < 4; ++mi) {
            bf16x8 a = ld8f(Wq + (size_t)(mi * 16 + l16) * C + kk * 32 + quad * 8);
            #pragma unroll
            for (int ni = 0; ni < 2; ++ni)
                qacc[mi][ni] = MFMA16(a, bq[ni], qacc[mi][ni]);
        }
    }
    // epilogue: +bias, *QSCALE, transpose-stage via per-wave slice of kc
    ushort* qs = kc + wv * (32 * 72);
    #pragma unroll
    for (int mi = 0; mi < 4; ++mi) {
        float4 bs = *(const float4*)(bias + h * HD + mi * 16 + quad * 4);
        #pragma unroll
        for (int ni = 0; ni < 2; ++ni)
            *(uint2*)(qs + (ni * 16 + l16) * 72 + mi * 16 + quad * 4) =
                pack4((qacc[mi][ni][0] + bs.x) * QSCALE,
                      (qacc[mi][ni][1] + bs.y) * QSCALE,
                      (qacc[mi][ni][2] + bs.z) * QSCALE,
                      (qacc[mi][ni][3] + bs.w) * QSCALE);
    }
    bf16x8 qf[2][2];   // B-frag [n=q][k=c'] held across attention
    #pragma unroll
    for (int ni = 0; ni < 2; ++ni)
        #pragma unroll
        for (int kk = 0; kk < 2; ++kk)
            qf[ni][kk] = lds8(qs + (ni * 16 + l16) * 72 + kk * 32 + quad * 8);
    __syncthreads();   // all qf loaded before kc is reused for K

    // ---- phase K+V (shared x fragments; x is both B of K-GEMM and A of V-GEMM)
    f32x4 kacc[4][4], vacc[4][4];
    #pragma unroll
    for (int mi = 0; mi < 4; ++mi)
        #pragma unroll
        for (int ni = 0; ni < 4; ++ni) { kacc[mi][ni] = z4; vacc[mi][ni] = z4; }

    #pragma unroll
    for (int kk = 0; kk < 4; ++kk) {
        bf16x8 x8[4];   // x rows wv*64 + i*16 + l16, ch chunk kk*32+quad*8
        #pragma unroll
        for (int i = 0; i < 4; ++i)
            x8[i] = ld8f(xb + (size_t)(wv * 64 + i * 16 + l16) * C + kk * 32 + quad * 8);
        #pragma unroll
        for (int mi = 0; mi < 4; ++mi) {           // K: A=Wk(m=c'), B=x(n=g)
            bf16x8 aw = ld8f(Wk + (size_t)(mi * 16 + l16) * C + kk * 32 + quad * 8);
            #pragma unroll
            for (int nt = 0; nt < 4; ++nt)
                kacc[mi][nt] = MFMA16(aw, x8[nt], kacc[mi][nt]);
        }
        #pragma unroll
        for (int nt = 0; nt < 4; ++nt) {           // V: A=x(m=g), B=Wv(n=c')
            bf16x8 bw = ld8f(Wv + (size_t)(nt * 16 + l16) * C + kk * 32 + quad * 8);
            #pragma unroll
            for (int mt = 0; mt < 4; ++mt)
                vacc[mt][nt] = MFMA16(x8[mt], bw, vacc[mt][nt]);
        }
    }
    // K epilogue: C/D col=g=l16, row=c' -> kc[g][c'] uint2 (stride 144B, 2-way free)
    #pragma unroll
    for (int mi = 0; mi < 4; ++mi) {
        float4 bs = *(const float4*)(bias + C + h * HD + mi * 16 + quad * 4);
        #pragma unroll
        for (int nt = 0; nt < 4; ++nt)
            *(uint2*)(kc + (wv * 64 + nt * 16 + l16) * 72 + mi * 16 + quad * 4) =
                pack4(kacc[mi][nt][0] + bs.x, kacc[mi][nt][1] + bs.y,
                      kacc[mi][nt][2] + bs.z, kacc[mi][nt][3] + bs.w);
    }
    // V epilogue: C/D col=c'=l16, row=g -> vc[c'][g] uint2 (stride 528B, 2-way)
    #pragma unroll
    for (int nt = 0; nt < 4; ++nt) {
        float bv = bias[2 * C + h * HD + nt * 16 + l16];
        #pragma unroll
        for (int mt = 0; mt < 4; ++mt)
            *(uint2*)(vc + (nt * 16 + l16) * 264 + wv * 64 + mt * 16 + quad * 4) =
                pack4(vacc[mt][nt][0] + bv, vacc[mt][nt][1] + bv,
                      vacc[mt][nt][2] + bv, vacc[mt][nt][3] + bv);
    }
    __syncthreads();   // K/V tiles ready for all waves

    // ---- attention (round-6 structure, K/V from LDS)
    ushort* ptw = pt + wv * (32 * 40);
    float lacc[2] = {0.f, 0.f};
    f32x4 oacc[4][2];
    #pragma unroll
    for (int mi = 0; mi < 4; ++mi)
        #pragma unroll
        for (int ni = 0; ni < 2; ++ni) oacc[mi][ni] = z4;

    #pragma unroll 2
    for (int sp = 0; sp < 8; ++sp) {
        const int g0 = sp * 32;   // 32-key strip

        bf16x8 kf[2][2];          // A-frag [m=g_k][k=c']
        #pragma unroll
        for (int kk = 0; kk < 2; ++kk)
            #pragma unroll
            for (int mi = 0; mi < 2; ++mi)
                kf[kk][mi] = lds8(kc + (g0 + mi * 16 + l16) * 72 + kk * 32 + quad * 8);

        // S^T [32 g_k][32 g_q]
        f32x4 s[2][2];
        #pragma unroll
        for (int mi = 0; mi < 2; ++mi)
            #pragma unroll
            for (int ni = 0; ni < 2; ++ni) s[mi][ni] = z4;
        #pragma unroll
        for (int kk = 0; kk < 2; ++kk)
            #pragma unroll
            for (int mi = 0; mi < 2; ++mi)
                #pragma unroll
                for (int ni = 0; ni < 2; ++ni)
                    s[mi][ni] = MFMA16(kf[kk][mi], qf[ni][kk], s[mi][ni]);

        // issue V fragments; latency hides under softmax VALU
        bf16x8 vf[4];
        #pragma unroll
        for (int mi = 0; mi < 4; ++mi)
            vf[mi] = lds8(vc + (mi * 16 + l16) * 264 + g0 + quad * 8);

        // single-pass softmax: p = exp2(s) (scale folded into Q; |s| small)
        #pragma unroll
        for (int mi = 0; mi < 2; ++mi)
            #pragma unroll
            for (int ni = 0; ni < 2; ++ni) {
                #pragma unroll
                for (int r = 0; r < 4; ++r) {
                    float p = exp2f(s[mi][ni][r]);
                    s[mi][ni][r] = p;
                    lacc[ni] += p;
                }
                *(uint2*)(ptw + (ni * 16 + l16) * 40 + mi * 16 + quad * 4) =
                    pack4(s[mi][ni][0], s[mi][ni][1], s[mi][ni][2], s[mi][ni][3]);
            }

        // O^T += V^T * P^T (wave-local pt: lgkmcnt ordering, no barrier)
        bf16x8 pf[2];
        #pragma unroll
        for (int ni = 0; ni < 2; ++ni)
            pf[ni] = lds8(ptw + (ni * 16 + l16) * 40 + quad * 8);
        #pragma unroll
        for (int mi = 0; mi < 4; ++mi)
            #pragma unroll
            for (int ni = 0; ni < 2; ++ni)
                oacc[mi][ni] = MFMA16(vf[mi], pf[ni], oacc[mi][ni]);
    }

    // epilogue: out[bl, g, h*64+c']; C/D row=c', col=g
    float* og = out + (size_t)bl * G * C + h * HD;
    #pragma unroll
    for (int ni = 0; ni < 2; ++ni) {
        float l = lacc[ni];
        l += __shfl_xor(l, 16);
        l += __shfl_xor(l, 32);
        float inv = 1.0f / l;
        int g = q0 + ni * 16 + l16;
        #pragma unroll
        for (int mi = 0; mi < 4; ++mi) {
            float4 st;
            st.x = oacc[mi][ni][0] * inv; st.y = oacc[mi][ni][1] * inv;
            st.z = oacc[mi][ni][2] * inv; st.w = oacc[mi][ni][3] * inv;
            *(float4*)(og + (size_t)g * C + mi * 16 + quad * 4) = st;
        }
    }
}

} // namespace dmsa

extern "C" void kernel_launch(void* const* d_in, const int* in_sizes, int n_in,
                              void* d_out, int out_size, void* d_ws, size_t ws_size,
                              hipStream_t stream) {
    (void)in_sizes; (void)n_in; (void)out_size; (void)d_ws; (void)ws_size;

    const float* x    = (const float*)d_in[0];
    const float* W    = (const float*)d_in[1];
    const float* bias = (const float*)d_in[2];
    float* out = (float*)d_out;

    dmsa::fused<<<dim3(2048), dim3(256), 0, stream>>>(x, W, bias, out);
}

// Round 3
// 177.742 us; speedup vs baseline: 1.4247x; 1.4247x over previous
//
#include <hip/hip_runtime.h>
#include <hip/hip_bf16.h>

// DilatedMSA round 8: convert-x pass + single fused (bl,h) kernel.
//  K0 convw: W [384][128] fp32 -> bf16 (ws).
//  K0b convx: x fp32 -> bf16 row-major (ws). Streaming, HBM-rate.
//  K1 fused: block = (bl, h), 4 waves x 64 queries (r5 attn tiling).
//    K/V-GEMM computed ONCE per (bl,h) (r7 duplicated it across qh blocks).
//    Same x fragments feed Q-GEMM(B), K-GEMM(B), V-GEMM(A); all-bf16 loads,
//    zero in-kernel cvt. Q-stage/K-epi/V-epi are wave-private LDS slices ->
//    ONE barrier total. setprio(1) around attn MFMA clusters.

typedef __bf16 bf16x8 __attribute__((ext_vector_type(8)));
typedef float  f32x4  __attribute__((ext_vector_type(4)));

#define MFMA16(a, b, c) __builtin_amdgcn_mfma_f32_16x16x32_bf16((a), (b), (c), 0, 0, 0)

namespace dmsa {

constexpr int G  = 256;    // tokens per (b,l)
constexpr int C  = 128;    // channels
constexpr int HD = 64;     // head dim
// fold log2(e)/sqrt(128) into Q -> attn does exp2(s) directly
constexpr float QSCALE = 1.4426950408889634f * 0.08838834764831845f;

__device__ __forceinline__ unsigned pack2(float a, float b) {
    union { __hip_bfloat162 h; unsigned u; } c;
    c.h = __float22bfloat162_rn(make_float2(a, b));   // v_cvt_pk_bf16_f32
    return c.u;
}
__device__ __forceinline__ uint2 pack4(float a, float b, float c, float d) {
    uint2 r; r.x = pack2(a, b); r.y = pack2(c, d); return r;
}
__device__ __forceinline__ uint4 pack8(const float* p) {
    uint4 r;
    r.x = pack2(p[0], p[1]); r.y = pack2(p[2], p[3]);
    r.z = pack2(p[4], p[5]); r.w = pack2(p[6], p[7]);
    return r;
}
__device__ __forceinline__ bf16x8 lds8(const ushort* p) { return *(const bf16x8*)p; }
__device__ __forceinline__ bf16x8 ldg8(const ushort* p) { return *(const bf16x8*)p; }

// ---------------------------------------------------------------------------
// K0: W [384][128] fp32 -> bf16.  24 blocks x 256 thr x 8 el.
// ---------------------------------------------------------------------------
__global__ void convw(const float* __restrict__ W, ushort* __restrict__ wbf) {
    int t = blockIdx.x * 256 + threadIdx.x;
    float tmp[8];
    const float* p = W + (size_t)t * 8;
    *(float4*)tmp       = *(const float4*)p;
    *(float4*)(tmp + 4) = *(const float4*)(p + 4);
    *(uint4*)(wbf + (size_t)t * 8) = pack8(tmp);
}

// ---------------------------------------------------------------------------
// K0b: x [512*256*128] fp32 -> bf16 row-major.  8192 blocks x 256 thr x 8 el.
// ---------------------------------------------------------------------------
__global__ void convx(const float* __restrict__ x, ushort* __restrict__ xbf) {
    size_t t = (size_t)blockIdx.x * 256 + threadIdx.x;
    float tmp[8];
    const float* p = x + t * 8;
    *(float4*)tmp       = *(const float4*)p;
    *(float4*)(tmp + 4) = *(const float4*)(p + 4);
    *(uint4*)(xbf + t * 8) = pack8(tmp);
}

// ---------------------------------------------------------------------------
// K1: grid 1024 = (bl 512) x (h 2), block 256 (4 waves).
// Wave wv owns rows/queries wv*64..+64 for Q/K/V-GEMM and attention.
// LDS 80896 B -> 2 blocks/CU.
// ---------------------------------------------------------------------------
__global__ __launch_bounds__(256, 2)
void fused(const ushort* __restrict__ xb, const ushort* __restrict__ wb,
           const float* __restrict__ bias, float* __restrict__ out)
{
    __shared__ ushort kc[G * 72];        // K [256 g][64 c' +pad8]; Q-stage first
    __shared__ ushort vc[HD * 264];      // V^T [64 c'][256 g +pad8]
    __shared__ ushort pt[4 * 32 * 40];   // per-wave P [32 q][32 k +pad8]

    const int tid = threadIdx.x, wv = tid >> 6, lane = tid & 63;
    const int l16 = lane & 15, quad = lane >> 4;

    // XCD-chunked bijective swizzle (1024 % 8 == 0): h=0/1 of one bl colocate.
    const int b  = blockIdx.x;
    const int L  = ((b & 7) << 7) | (b >> 3);
    const int bl = L >> 1, h = L & 1;

    const ushort* xr = xb + (size_t)bl * G * C;
    const ushort* Wq = wb + (size_t)(h * HD) * C;
    const ushort* Wk = wb + (size_t)(C + h * HD) * C;
    const ushort* Wv = wb + (size_t)(2 * C + h * HD) * C;

    const int r0 = wv * 64;              // wave's token range (rows AND queries)
    const f32x4 z4 = {0.f, 0.f, 0.f, 0.f};

    // ---- Q-GEMM: Q^T [c'][q]. A=Wq (m=c', 4 tiles), B=x rows r0.. (4 ni).
    f32x4 qacc[4][4];
    #pragma unroll
    for (int mi = 0; mi < 4; ++mi)
        #pragma unroll
        for (int ni = 0; ni < 4; ++ni) qacc[mi][ni] = z4;

    #pragma unroll
    for (int kk = 0; kk < 4; ++kk) {
        bf16x8 bx[4];
        #pragma unroll
        for (int ni = 0; ni < 4; ++ni)
            bx[ni] = ldg8(xr + (size_t)(r0 + ni * 16 + l16) * C + kk * 32 + quad * 8);
        #pragma unroll
        for (int mi = 0; mi < 4; ++mi) {
            bf16x8 a = ldg8(Wq + (size_t)(mi * 16 + l16) * C + kk * 32 + quad * 8);
            #pragma unroll
            for (int ni = 0; ni < 4; ++ni)
                qacc[mi][ni] = MFMA16(a, bx[ni], qacc[mi][ni]);
        }
    }
    // stage to wave-private kc slice (+bias, *QSCALE), read back B-frags
    ushort* qs = kc + r0 * 72;
    #pragma unroll
    for (int mi = 0; mi < 4; ++mi) {
        float4 bs = *(const float4*)(bias + h * HD + mi * 16 + quad * 4);
        #pragma unroll
        for (int ni = 0; ni < 4; ++ni)
            *(uint2*)(qs + (ni * 16 + l16) * 72 + mi * 16 + quad * 4) =
                pack4((qacc[mi][ni][0] + bs.x) * QSCALE,
                      (qacc[mi][ni][1] + bs.y) * QSCALE,
                      (qacc[mi][ni][2] + bs.z) * QSCALE,
                      (qacc[mi][ni][3] + bs.w) * QSCALE);
    }
    bf16x8 qf[4][2];   // B-frag [n=q][k=c'] held across attention
    #pragma unroll
    for (int ni = 0; ni < 4; ++ni)
        #pragma unroll
        for (int kh = 0; kh < 2; ++kh)
            qf[ni][kh] = lds8(qs + (ni * 16 + l16) * 72 + kh * 32 + quad * 8);

    // ---- K-GEMM: A=Wk (m=c'), B=x rows r0.. (4 nt). Epi overwrites own slice.
    {
        f32x4 kacc[4][4];
        #pragma unroll
        for (int mi = 0; mi < 4; ++mi)
            #pragma unroll
            for (int nt = 0; nt < 4; ++nt) kacc[mi][nt] = z4;
        #pragma unroll
        for (int kk = 0; kk < 4; ++kk) {
            bf16x8 bx[4];
            #pragma unroll
            for (int nt = 0; nt < 4; ++nt)
                bx[nt] = ldg8(xr + (size_t)(r0 + nt * 16 + l16) * C + kk * 32 + quad * 8);
            #pragma unroll
            for (int mi = 0; mi < 4; ++mi) {
                bf16x8 a = ldg8(Wk + (size_t)(mi * 16 + l16) * C + kk * 32 + quad * 8);
                #pragma unroll
                for (int nt = 0; nt < 4; ++nt)
                    kacc[mi][nt] = MFMA16(a, bx[nt], kacc[mi][nt]);
            }
        }
        // C/D col=g=l16, row=c' -> kc[g][c'] (wave-private rows r0..+64)
        #pragma unroll
        for (int mi = 0; mi < 4; ++mi) {
            float4 bs = *(const float4*)(bias + C + h * HD + mi * 16 + quad * 4);
            #pragma unroll
            for (int nt = 0; nt < 4; ++nt)
                *(uint2*)(kc + (r0 + nt * 16 + l16) * 72 + mi * 16 + quad * 4) =
                    pack4(kacc[mi][nt][0] + bs.x, kacc[mi][nt][1] + bs.y,
                          kacc[mi][nt][2] + bs.z, kacc[mi][nt][3] + bs.w);
        }
    }

    // ---- V-GEMM: A=x rows r0.. (4 mt), B=Wv (4 nt). Epi: disjoint vc columns.
    {
        f32x4 vacc[4][4];
        #pragma unroll
        for (int mt = 0; mt < 4; ++mt)
            #pragma unroll
            for (int nt = 0; nt < 4; ++nt) vacc[mt][nt] = z4;
        #pragma unroll
        for (int kk = 0; kk < 4; ++kk) {
            bf16x8 ax[4];
            #pragma unroll
            for (int mt = 0; mt < 4; ++mt)
                ax[mt] = ldg8(xr + (size_t)(r0 + mt * 16 + l16) * C + kk * 32 + quad * 8);
            #pragma unroll
            for (int nt = 0; nt < 4; ++nt) {
                bf16x8 bw = ldg8(Wv + (size_t)(nt * 16 + l16) * C + kk * 32 + quad * 8);
                #pragma unroll
                for (int mt = 0; mt < 4; ++mt)
                    vacc[mt][nt] = MFMA16(ax[mt], bw, vacc[mt][nt]);
            }
        }
        // C/D col=c'=l16, row=g -> vc[c'][g] (all rows, wave's 64-token columns)
        #pragma unroll
        for (int nt = 0; nt < 4; ++nt) {
            float bv = bias[2 * C + h * HD + nt * 16 + l16];
            #pragma unroll
            for (int mt = 0; mt < 4; ++mt)
                *(uint2*)(vc + (nt * 16 + l16) * 264 + r0 + mt * 16 + quad * 4) =
                    pack4(vacc[mt][nt][0] + bv, vacc[mt][nt][1] + bv,
                          vacc[mt][nt][2] + bv, vacc[mt][nt][3] + bv);
        }
    }

    __syncthreads();   // K/V tiles ready for all waves (the only barrier)

    // ---- attention: wave's 64 queries (qf) vs all 256 keys, 8x 32-key strips
    ushort* ptw = pt + wv * (32 * 40);
    float lacc[4] = {0.f, 0.f, 0.f, 0.f};
    f32x4 oacc[4][4];
    #pragma unroll
    for (int mi = 0; mi < 4; ++mi)
        #pragma unroll
        for (int ni = 0; ni < 4; ++ni) oacc[mi][ni] = z4;

    #pragma unroll 2
    for (int sp = 0; sp < 8; ++sp) {
        const int g0 = sp * 32;

        bf16x8 kf[2][2];          // A-frag [k-half][m=g_k]
        #pragma unroll
        for (int kh = 0; kh < 2; ++kh)
            #pragma unroll
            for (int mi = 0; mi < 2; ++mi)
                kf[kh][mi] = lds8(kc + (g0 + mi * 16 + l16) * 72 + kh * 32 + quad * 8);
        bf16x8 vf[4];             // A-frag [m=c'] for this strip
        #pragma unroll
        for (int mi = 0; mi < 4; ++mi)
            vf[mi] = lds8(vc + (mi * 16 + l16) * 264 + g0 + quad * 8);

        #pragma unroll
        for (int nig = 0; nig < 2; ++nig) {   // two 32-query halves through ptw
            // S^T [32 g_k][32 g_q]
            f32x4 s[2][2];
            #pragma unroll
            for (int mi = 0; mi < 2; ++mi)
                #pragma unroll
                for (int nj = 0; nj < 2; ++nj) s[mi][nj] = z4;
            __builtin_amdgcn_s_setprio(1);
            #pragma unroll
            for (int kh = 0; kh < 2; ++kh)
                #pragma unroll
                for (int mi = 0; mi < 2; ++mi)
                    #pragma unroll
                    for (int nj = 0; nj < 2; ++nj)
                        s[mi][nj] = MFMA16(kf[kh][mi], qf[nig * 2 + nj][kh], s[mi][nj]);
            __builtin_amdgcn_s_setprio(0);

            // single-pass softmax: p = exp2(s) (scale folded into Q; |s| small)
            #pragma unroll
            for (int mi = 0; mi < 2; ++mi)
                #pragma unroll
                for (int nj = 0; nj < 2; ++nj) {
                    #pragma unroll
                    for (int r = 0; r < 4; ++r) {
                        float p = exp2f(s[mi][nj][r]);
                        s[mi][nj][r] = p;
                        lacc[nig * 2 + nj] += p;
                    }
                    *(uint2*)(ptw + (nj * 16 + l16) * 40 + mi * 16 + quad * 4) =
                        pack4(s[mi][nj][0], s[mi][nj][1], s[mi][nj][2], s[mi][nj][3]);
                }

            // O^T += V^T * P^T (wave-local ptw: in-order LDS pipe, no barrier)
            bf16x8 pf[2];
            #pragma unroll
            for (int nj = 0; nj < 2; ++nj)
                pf[nj] = lds8(ptw + (nj * 16 + l16) * 40 + quad * 8);
            __builtin_amdgcn_s_setprio(1);
            #pragma unroll
            for (int mi = 0; mi < 4; ++mi)
                #pragma unroll
                for (int nj = 0; nj < 2; ++nj)
                    oacc[mi][nig * 2 + nj] = MFMA16(vf[mi], pf[nj], oacc[mi][nig * 2 + nj]);
            __builtin_amdgcn_s_setprio(0);
        }
    }

    // epilogue: out[bl, g, h*64+c']; C/D row=c', col=g
    float* og = out + (size_t)bl * G * C + h * HD;
    #pragma unroll
    for (int ni = 0; ni < 4; ++ni) {
        float l = lacc[ni];
        l += __shfl_xor(l, 16);
        l += __shfl_xor(l, 32);
        float inv = 1.0f / l;
        int g = r0 + ni * 16 + l16;
        #pragma unroll
        for (int mi = 0; mi < 4; ++mi) {
            float4 st;
            st.x = oacc[mi][ni][0] * inv; st.y = oacc[mi][ni][1] * inv;
            st.z = oacc[mi][ni][2] * inv; st.w = oacc[mi][ni][3] * inv;
            *(float4*)(og + (size_t)g * C + mi * 16 + quad * 4) = st;
        }
    }
}

} // namespace dmsa

extern "C" void kernel_launch(void* const* d_in, const int* in_sizes, int n_in,
                              void* d_out, int out_size, void* d_ws, size_t ws_size,
                              hipStream_t stream) {
    (void)in_sizes; (void)n_in; (void)out_size;

    const size_t XBF = (size_t)512 * 256 * 128;          // x elements
    if (ws_size < XBF * 2 + 384 * 128 * 2) return;       // 33.65 MB needed

    const float* x    = (const float*)d_in[0];
    const float* W    = (const float*)d_in[1];
    const float* bias = (const float*)d_in[2];
    float* out = (float*)d_out;

    ushort* xbf = (ushort*)d_ws;
    ushort* wbf = xbf + XBF;

    dmsa::convw<<<dim3(24),   dim3(256), 0, stream>>>(W, wbf);
    dmsa::convx<<<dim3(8192), dim3(256), 0, stream>>>(x, xbf);
    dmsa::fused<<<dim3(1024), dim3(256), 0, stream>>>(xbf, wbf, bias, out);
}

// Round 4
// 166.054 us; speedup vs baseline: 1.5250x; 1.0704x over previous
//
#include <hip/hip_runtime.h>
#include <hip/hip_bf16.h>

// DilatedMSA round 9: convw + single fused kernel, in-register P (T12).
//  - attn phase rewritten on 32x32x16 MFMA: S^T lane-local per query column;
//    P -> PV B-frag via cvt_pk + permlane32_swap (NO pt LDS round-trip, the
//    invariant serial chain that pinned r5/r6/r8 attn at 78us).
//  - x fp32 -> bf16 fragments converted ONCE in-kernel (registers), reused by
//    Q/K/V GEMMs -> convx kernel deleted.
//  - LDS: kc 36.9K + vc 33.8K = 70.7KB (pt gone), 2 blocks/CU, ONE barrier.

typedef __bf16 bf16x8 __attribute__((ext_vector_type(8)));
typedef float  f32x4  __attribute__((ext_vector_type(4)));
typedef float  f32x16 __attribute__((ext_vector_type(16)));

#define MFMA16(a, b, c) __builtin_amdgcn_mfma_f32_16x16x32_bf16((a), (b), (c), 0, 0, 0)
#define MFMA32(a, b, c) __builtin_amdgcn_mfma_f32_32x32x16_bf16((a), (b), (c), 0, 0, 0)

namespace dmsa {

constexpr int G  = 256;    // tokens per (b,l)
constexpr int C  = 128;    // channels
constexpr int HD = 64;     // head dim
// fold log2(e)/sqrt(128) into Q -> attn does exp2(s) directly
constexpr float QSCALE = 1.4426950408889634f * 0.08838834764831845f;

__device__ __forceinline__ unsigned pack2(float a, float b) {
    union { __hip_bfloat162 h; unsigned u; } c;
    c.h = __float22bfloat162_rn(make_float2(a, b));   // v_cvt_pk_bf16_f32
    return c.u;
}
__device__ __forceinline__ uint2 pack4(float a, float b, float c, float d) {
    uint2 r; r.x = pack2(a, b); r.y = pack2(c, d); return r;
}
__device__ __forceinline__ uint4 pack8(const float* p) {
    uint4 r;
    r.x = pack2(p[0], p[1]); r.y = pack2(p[2], p[3]);
    r.z = pack2(p[4], p[5]); r.w = pack2(p[6], p[7]);
    return r;
}
__device__ __forceinline__ bf16x8 lds8(const ushort* p) { return *(const bf16x8*)p; }
__device__ __forceinline__ bf16x8 ldg8(const ushort* p) { return *(const bf16x8*)p; }
// 8 consecutive fp32 -> bf16x8 fragment
__device__ __forceinline__ bf16x8 ld8f(const float* __restrict__ p) {
    float t[8];
    *(float4*)t       = *(const float4*)p;
    *(float4*)(t + 4) = *(const float4*)(p + 4);
    union { uint4 u; bf16x8 v; } c;
    c.u = pack8(t);
    return c.v;
}

// ---------------------------------------------------------------------------
// K0: W [384][128] fp32 -> bf16.
// ---------------------------------------------------------------------------
__global__ void convw(const float* __restrict__ W, ushort* __restrict__ wbf) {
    int t = blockIdx.x * 256 + threadIdx.x;
    float tmp[8];
    const float* p = W + (size_t)t * 8;
    *(float4*)tmp       = *(const float4*)p;
    *(float4*)(tmp + 4) = *(const float4*)(p + 4);
    *(uint4*)(wbf + (size_t)t * 8) = pack8(tmp);
}

// ---------------------------------------------------------------------------
// K1: grid 1024 = (bl 512) x (h 2), block 256 (4 waves).
// Wave wv owns tokens/queries wv*64..+64 for the GEMMs and attention.
// ---------------------------------------------------------------------------
__global__ __launch_bounds__(256, 2)
void fused(const float* __restrict__ x, const ushort* __restrict__ wb,
           const float* __restrict__ bias, float* __restrict__ out)
{
    __shared__ ushort kc[G * 72];        // K [256 g][64 c' +pad8]; Q-stage first
    __shared__ ushort vc[HD * 264];      // V^T [64 c'][256 g +pad8]

    const int tid = threadIdx.x, wv = tid >> 6, lane = tid & 63;
    const int l16 = lane & 15, quad = lane >> 4;
    const int l32 = lane & 31, hl = lane >> 5;

    // XCD-chunked bijective swizzle (1024 % 8 == 0): h=0/1 of one bl colocate.
    const int b  = blockIdx.x;
    const int L  = ((b & 7) << 7) | (b >> 3);
    const int bl = L >> 1, h = L & 1;

    const float*  xr = x  + (size_t)bl * G * C;
    const ushort* Wq = wb + (size_t)(h * HD) * C;
    const ushort* Wk = wb + (size_t)(C + h * HD) * C;
    const ushort* Wv = wb + (size_t)(2 * C + h * HD) * C;

    const int r0 = wv * 64;
    const f32x4 z4 = {0.f, 0.f, 0.f, 0.f};

    // ---- x fragments: fp32 -> bf16 ONCE, reused by Q(B), K(B), V(A) GEMMs.
    // frag layout [row/col = l16][k = quad*8+j] serves both A and B roles.
    bf16x8 xf[4][4];   // [16-row tile][32-ch chunk]
    #pragma unroll
    for (int i = 0; i < 4; ++i)
        #pragma unroll
        for (int kk = 0; kk < 4; ++kk)
            xf[i][kk] = ld8f(xr + (size_t)(r0 + i * 16 + l16) * C + kk * 32 + quad * 8);

    // ---- Q-GEMM: Q^T [c'][q]. A=Wq (m=c', 4 tiles), B=xf.
    f32x4 qacc[4][4];
    #pragma unroll
    for (int mi = 0; mi < 4; ++mi)
        #pragma unroll
        for (int ni = 0; ni < 4; ++ni) qacc[mi][ni] = z4;
    #pragma unroll
    for (int kk = 0; kk < 4; ++kk)
        #pragma unroll
        for (int mi = 0; mi < 4; ++mi) {
            bf16x8 a = ldg8(Wq + (size_t)(mi * 16 + l16) * C + kk * 32 + quad * 8);
            #pragma unroll
            for (int ni = 0; ni < 4; ++ni)
                qacc[mi][ni] = MFMA16(a, xf[ni][kk], qacc[mi][ni]);
        }
    // stage to wave-private kc slice (+bias, *QSCALE): qs[q][c']
    ushort* qs = kc + r0 * 72;
    #pragma unroll
    for (int mi = 0; mi < 4; ++mi) {
        float4 bs = *(const float4*)(bias + h * HD + mi * 16 + quad * 4);
        #pragma unroll
        for (int ni = 0; ni < 4; ++ni)
            *(uint2*)(qs + (ni * 16 + l16) * 72 + mi * 16 + quad * 4) =
                pack4((qacc[mi][ni][0] + bs.x) * QSCALE,
                      (qacc[mi][ni][1] + bs.y) * QSCALE,
                      (qacc[mi][ni][2] + bs.z) * QSCALE,
                      (qacc[mi][ni][3] + bs.w) * QSCALE);
    }
    // read back as 32x32x16 B-frags: B[n=q=l32][k=c'=(hl*8..)+16kk]
    bf16x8 qf[2][4];
    #pragma unroll
    for (int ni = 0; ni < 2; ++ni)
        #pragma unroll
        for (int kk = 0; kk < 4; ++kk)
            qf[ni][kk] = lds8(qs + (ni * 32 + l32) * 72 + kk * 16 + hl * 8);

    // ---- K-GEMM: A=Wk (m=c'), B=xf. Epi overwrites own kc slice.
    {
        f32x4 kacc[4][4];
        #pragma unroll
        for (int mi = 0; mi < 4; ++mi)
            #pragma unroll
            for (int nt = 0; nt < 4; ++nt) kacc[mi][nt] = z4;
        #pragma unroll
        for (int kk = 0; kk < 4; ++kk)
            #pragma unroll
            for (int mi = 0; mi < 4; ++mi) {
                bf16x8 a = ldg8(Wk + (size_t)(mi * 16 + l16) * C + kk * 32 + quad * 8);
                #pragma unroll
                for (int nt = 0; nt < 4; ++nt)
                    kacc[mi][nt] = MFMA16(a, xf[nt][kk], kacc[mi][nt]);
            }
        // C/D col=g=l16, row=c' -> kc[g][c']
        #pragma unroll
        for (int mi = 0; mi < 4; ++mi) {
            float4 bs = *(const float4*)(bias + C + h * HD + mi * 16 + quad * 4);
            #pragma unroll
            for (int nt = 0; nt < 4; ++nt)
                *(uint2*)(kc + (r0 + nt * 16 + l16) * 72 + mi * 16 + quad * 4) =
                    pack4(kacc[mi][nt][0] + bs.x, kacc[mi][nt][1] + bs.y,
                          kacc[mi][nt][2] + bs.z, kacc[mi][nt][3] + bs.w);
        }
    }

    // ---- V-GEMM: A=xf (m=tok), B=Wv (n=c'). Epi: disjoint vc columns.
    {
        f32x4 vacc[4][4];
        #pragma unroll
        for (int mt = 0; mt < 4; ++mt)
            #pragma unroll
            for (int nt = 0; nt < 4; ++nt) vacc[mt][nt] = z4;
        #pragma unroll
        for (int kk = 0; kk < 4; ++kk)
            #pragma unroll
            for (int nt = 0; nt < 4; ++nt) {
                bf16x8 bw = ldg8(Wv + (size_t)(nt * 16 + l16) * C + kk * 32 + quad * 8);
                #pragma unroll
                for (int mt = 0; mt < 4; ++mt)
                    vacc[mt][nt] = MFMA16(xf[mt][kk], bw, vacc[mt][nt]);
            }
        // C/D col=c'=l16, row=g -> vc[c'][g]
        #pragma unroll
        for (int nt = 0; nt < 4; ++nt) {
            float bv = bias[2 * C + h * HD + nt * 16 + l16];
            #pragma unroll
            for (int mt = 0; mt < 4; ++mt)
                *(uint2*)(vc + (nt * 16 + l16) * 264 + r0 + mt * 16 + quad * 4) =
                    pack4(vacc[mt][nt][0] + bv, vacc[mt][nt][1] + bv,
                          vacc[mt][nt][2] + bv, vacc[mt][nt][3] + bv);
        }
    }

    __syncthreads();   // K/V tiles ready for all waves (the only barrier)

    // ---- attention, 32x32x16. Wave's 64 queries = two 32-col tiles (ni).
    // S^T C/D: col=q=l32, row=g_k=(reg&3)+8*(reg>>2)+4*hl (+32*sp).
    float lacc[2] = {0.f, 0.f};
    f32x16 oacc[2][2];
    #pragma unroll
    for (int mt = 0; mt < 2; ++mt)
        #pragma unroll
        for (int ni = 0; ni < 2; ++ni)
            #pragma unroll
            for (int r = 0; r < 16; ++r) oacc[mt][ni][r] = 0.f;

    #pragma unroll 2
    for (int sp = 0; sp < 8; ++sp) {
        const int g0 = sp * 32;

        bf16x8 kf[4];             // A[m=g_k=l32][k=c' chunk kk*16+hl*8]
        #pragma unroll
        for (int kk = 0; kk < 4; ++kk)
            kf[kk] = lds8(kc + (g0 + l32) * 72 + kk * 16 + hl * 8);
        bf16x8 vf[2][2];          // A[m=c'=mt*32+l32][k=g_k chunk ch*16+hl*8]
        #pragma unroll
        for (int mt = 0; mt < 2; ++mt)
            #pragma unroll
            for (int ch = 0; ch < 2; ++ch)
                vf[mt][ch] = lds8(vc + (mt * 32 + l32) * 264 + g0 + ch * 16 + hl * 8);

        #pragma unroll
        for (int ni = 0; ni < 2; ++ni) {
            f32x16 s;
            #pragma unroll
            for (int r = 0; r < 16; ++r) s[r] = 0.f;
            __builtin_amdgcn_s_setprio(1);
            #pragma unroll
            for (int kk = 0; kk < 4; ++kk)
                s = MFMA32(kf[kk], qf[ni][kk], s);
            __builtin_amdgcn_s_setprio(0);

            // softmax: p = exp2(s) lane-local (each lane = one query column)
            float part = 0.f;
            #pragma unroll
            for (int r = 0; r < 16; ++r) {
                float p = exp2f(s[r]);
                s[r] = p;
                part += p;
            }
            lacc[ni] += part;

            // P -> PV B-frag IN REGISTERS: cvt_pk pairs + permlane32_swap.
            // For chunk ch (k rows g0+ch*16..+16): regs 8ch..8ch+3 pair with
            // regs 8ch+4..8ch+7 of the opposite lane-half (T12 pattern).
            #pragma unroll
            for (int ch = 0; ch < 2; ++ch) {
                unsigned p0a = pack2(s[8 * ch + 0], s[8 * ch + 1]);
                unsigned p0b = pack2(s[8 * ch + 2], s[8 * ch + 3]);
                unsigned p1a = pack2(s[8 * ch + 4], s[8 * ch + 5]);
                unsigned p1b = pack2(s[8 * ch + 6], s[8 * ch + 7]);
                auto w02 = __builtin_amdgcn_permlane32_swap((int)p0a, (int)p1a, false, false);
                auto w13 = __builtin_amdgcn_permlane32_swap((int)p0b, (int)p1b, false, false);
                union { uint4 u; bf16x8 v; } pf;
                pf.u.x = (unsigned)w02[0]; pf.u.y = (unsigned)w13[0];
                pf.u.z = (unsigned)w02[1]; pf.u.w = (unsigned)w13[1];
                __builtin_amdgcn_s_setprio(1);
                #pragma unroll
                for (int mt = 0; mt < 2; ++mt)
                    oacc[mt][ni] = MFMA32(vf[mt][ch], pf.v, oacc[mt][ni]);
                __builtin_amdgcn_s_setprio(0);
            }
        }
    }

    // epilogue: out[bl, g, h*64+c']; O^T C/D: col=q=l32, row=c'=e+8rr+4hl+32mt
    float* og = out + (size_t)bl * G * C + h * HD;
    #pragma unroll
    for (int ni = 0; ni < 2; ++ni) {
        float l = lacc[ni];
        l += __shfl_xor(l, 32);          // rows split only across lane halves
        float inv = 1.0f / l;
        int g = r0 + ni * 32 + l32;
        #pragma unroll
        for (int mt = 0; mt < 2; ++mt)
            #pragma unroll
            for (int rr = 0; rr < 4; ++rr) {
                float4 st;
                st.x = oacc[mt][ni][4 * rr + 0] * inv;
                st.y = oacc[mt][ni][4 * rr + 1] * inv;
                st.z = oacc[mt][ni][4 * rr + 2] * inv;
                st.w = oacc[mt][ni][4 * rr + 3] * inv;
                *(float4*)(og + (size_t)g * C + mt * 32 + rr * 8 + hl * 4) = st;
            }
    }
}

} // namespace dmsa

extern "C" void kernel_launch(void* const* d_in, const int* in_sizes, int n_in,
                              void* d_out, int out_size, void* d_ws, size_t ws_size,
                              hipStream_t stream) {
    (void)in_sizes; (void)n_in; (void)out_size;

    if (ws_size < (size_t)384 * 128 * 2) return;   // 96 KB W-bf16 scratch

    const float* x    = (const float*)d_in[0];
    const float* W    = (const float*)d_in[1];
    const float* bias = (const float*)d_in[2];
    float* out = (float*)d_out;

    ushort* wbf = (ushort*)d_ws;

    dmsa::convw<<<dim3(24),   dim3(256), 0, stream>>>(W, wbf);
    dmsa::fused<<<dim3(1024), dim3(256), 0, stream>>>(x, wbf, bias, out);
}